// Round 5
// baseline (630.733 us; speedup 1.0000x reference)
//
#include <hip/hip_runtime.h>
#include <hip/hip_bf16.h>
#include <stdint.h>

#define B_ 32
#define T_ 2048
#define H_ 1024
#define M_ (B_*T_)

typedef __bf16 bf16x8 __attribute__((ext_vector_type(8)));
typedef float  f32x4  __attribute__((ext_vector_type(4)));
typedef float  f32x16 __attribute__((ext_vector_type(16)));

__device__ __forceinline__ float tanh_fast(float x) {
    float e = __expf(2.0f * x);
    return 1.0f - 2.0f / (e + 1.0f);
}

__device__ __forceinline__ bf16x8 cvt2(f32x4 f0, f32x4 f1) {
    bf16x8 h;
    h[0] = (__bf16)f0[0]; h[1] = (__bf16)f0[1]; h[2] = (__bf16)f0[2]; h[3] = (__bf16)f0[3];
    h[4] = (__bf16)f1[0]; h[5] = (__bf16)f1[1]; h[6] = (__bf16)f1[2]; h[7] = (__bf16)f1[3];
    return h;
}

// async global->LDS DMA, 16B per lane; LDS dest is wave-uniform base + lane*16
__device__ __forceinline__ void dma16(const void* g, void* l) {
    __builtin_amdgcn_global_load_lds(
        (const __attribute__((address_space(1))) unsigned int*)g,
        (__attribute__((address_space(3))) unsigned int*)l, 16, 0, 0);
}

// ---------------- K0: fused prep (W_enc -> Wt fragment tiles ; dec_p matvec) ----------------
// Wt cell tg = (s*32 + c)*64 + lane ; holds W[o=c*32+(lane&31)][k=s*16+(lane>>5)*8 .. +8]
__global__ __launch_bounds__(256) void k_prep(const float* __restrict__ We,
                                              __bf16* __restrict__ Wt,
                                              const float* __restrict__ dec,
                                              const float* __restrict__ Wd,
                                              float* __restrict__ decp) {
    int bx = blockIdx.x;
    int tid = threadIdx.x;
    if (bx < 512) {
        int tg = bx * 256 + tid;
        int lane = tg & 63;
        int c = (tg >> 6) & 31;
        int s = tg >> 11;
        int o = c * 32 + (lane & 31);
        int k = s * 16 + (lane >> 5) * 8;
        const f32x4* src = (const f32x4*)&We[(size_t)o * H_ + k];
        *(bf16x8*)&Wt[(size_t)tg * 8] = cvt2(src[0], src[1]);
    } else {
        int bxd = bx - 512;
        int b = bxd & 31, oc = bxd >> 5;
        int o = oc * 64 + (tid >> 2);
        int kq = tid & 3;
        const f32x4* wr = (const f32x4*)&Wd[(size_t)o * H_ + kq * 256];
        const f32x4* dr = (const f32x4*)&dec[(size_t)b * H_ + kq * 256];
        f32x4 s4 = {0.f, 0.f, 0.f, 0.f};
#pragma unroll 8
        for (int i = 0; i < 64; ++i) s4 += wr[i] * dr[i];
        float s = s4[0] + s4[1] + s4[2] + s4[3];
        s += __shfl_xor(s, 1);
        s += __shfl_xor(s, 2);
        if (kq == 0) decp[b * H_ + o] = s;
    }
}

// ---------------- K0b: convert+tile enc fp32 -> encT bf16 fragment-major ----------------
// encT[rg:512][kc:8][g:32][lane:64][8] ; g = s*4+rt ; row = rt*32+(lane&31) (local to rg*128),
// k = kc*128 + s*16 + (lane>>5)*8. Each (rg,kc) chunk is a contiguous 32 KB DMA source.
__global__ __launch_bounds__(256) void k_conv(const float* __restrict__ enc,
                                              __bf16* __restrict__ encT) {
    __shared__ float Lf[128][132];
    const int rg = blockIdx.x;           // 0..511
    const int t = threadIdx.x;
    const size_t rowbase = (size_t)rg * 128;
#pragma unroll 1
    for (int kc = 0; kc < 8; ++kc) {
        // load 128 rows x 128 k fp32, coalesced
#pragma unroll
        for (int i = 0; i < 16; ++i) {
            int row = i * 8 + (t >> 5);
            int qq = t & 31;
            f32x4 val = *(const f32x4*)&enc[(rowbase + row) * H_ + kc * 128 + qq * 4];
            *(f32x4*)&Lf[row][qq * 4] = val;
        }
        __syncthreads();
        // emit fragment-major bf16 cells, coalesced writes
#pragma unroll
        for (int j = 0; j < 8; ++j) {
            int cid = j * 256 + t;        // 0..2047
            int g = cid >> 6;
            int lane = cid & 63;
            int rt = g & 3, s = g >> 2;
            int row = rt * 32 + (lane & 31);
            int kl = s * 16 + (lane >> 5) * 8;
            f32x4 f0 = *(const f32x4*)&Lf[row][kl];
            f32x4 f1 = *(const f32x4*)&Lf[row][kl + 4];
            *(bf16x8*)&encT[((((size_t)rg * 8 + kc) * 32 + g) * 64 + lane) * 8] = cvt2(f0, f1);
        }
        __syncthreads();
    }
}

// ---------------- K1: GEMM(32x32x16) via global_load_lds + tanh + dot(v) -> score partials ----
// 2048 blocks = 512 rg (128 rows) x 4 ng (256 cols), 512 threads = 8 waves (2 wr x 4 wc).
// Wave = 64 rows x 64 cols = 2rr x 2ct MFMA tiles, acc 64 VGPR. A staged by DMA (double buf),
// B 2-deep register ring from L2-resident Wt. One barrier per K-chunk.
__global__ __launch_bounds__(512, 4) void k_scores(const __bf16* __restrict__ encT,
                                                   const float* __restrict__ decp,
                                                   const __bf16* __restrict__ Wt,
                                                   const float* __restrict__ v,
                                                   float* __restrict__ scores_p) {
    __shared__ __align__(16) __bf16 Abuf[2][32 * 64 * 8];   // 2 x 32 KB
    __shared__ float red[4][128];

    const int tid = threadIdx.x;
    const int w = tid >> 6, lane = tid & 63;
    const int l5 = lane & 31, q2 = lane >> 5;
    const int wr = w >> 2, wc = w & 3;

    // XCD-swizzled block decode
    const int bx = blockIdx.x;
    const int xs = bx & 7;
    const int q = bx >> 3;
    const int ng = q & 3;                   // 256-col group
    const int rg = (q >> 2) * 8 + xs;       // 0..511
    const int m0 = rg * 128;
    const int b = m0 >> 11;
    const int c0 = ng * 8 + wc * 2;         // global 32-col tile index

    // acc init with dec_p folded in
    f32x16 acc[2][2];
#pragma unroll
    for (int ct = 0; ct < 2; ++ct) {
        float dpv = decp[b * H_ + (c0 + ct) * 32 + l5];
#pragma unroll
        for (int rr = 0; rr < 2; ++rr)
#pragma unroll
            for (int g = 0; g < 16; ++g)
                acc[rr][ct][g] = dpv;
    }

    const size_t chunk0 = ((size_t)rg * 8) * 32 * 512;   // elem offset of (rg, kc=0)

    // ---- prologue: DMA chunk 0 into buf 0 (each wave stages groups w*4..w*4+3) ----
#pragma unroll
    for (int i = 0; i < 4; ++i) {
        int g = w * 4 + i;
        dma16(&encT[chunk0 + (size_t)g * 512 + lane * 8], &Abuf[0][g * 512]);
    }
    __syncthreads();

    bf16x8 b_cur[2], b_nxt[2];
#pragma unroll
    for (int ct = 0; ct < 2; ++ct)
        b_cur[ct] = *(const bf16x8*)&Wt[(((size_t)0 * 32 + c0 + ct) * 64 + lane) * 8];

#pragma unroll 1
    for (int kc = 0; kc < 8; ++kc) {
        // DMA next chunk into the other buffer (drained by this chunk's end barrier)
        if (kc < 7) {
            const size_t cb = ((size_t)(rg * 8 + kc + 1)) * 32 * 512;
#pragma unroll
            for (int i = 0; i < 4; ++i) {
                int g = w * 4 + i;
                dma16(&encT[cb + (size_t)g * 512 + lane * 8], &Abuf[(kc + 1) & 1][g * 512]);
            }
        }
        const __bf16* buf = Abuf[kc & 1];

#pragma unroll
        for (int sl = 0; sl < 8; ++sl) {
            int sgn = (kc * 8 + sl + 1) & 63;
#pragma unroll
            for (int ct = 0; ct < 2; ++ct)
                b_nxt[ct] = *(const bf16x8*)&Wt[(((size_t)sgn * 32 + c0 + ct) * 64 + lane) * 8];

            bf16x8 af[2];
#pragma unroll
            for (int rr = 0; rr < 2; ++rr)
                af[rr] = *(const bf16x8*)&buf[((sl * 4 + wr * 2 + rr) * 64 + lane) * 8];

            acc[0][0] = __builtin_amdgcn_mfma_f32_32x32x16_bf16(af[0], b_cur[0], acc[0][0], 0, 0, 0);
            acc[0][1] = __builtin_amdgcn_mfma_f32_32x32x16_bf16(af[0], b_cur[1], acc[0][1], 0, 0, 0);
            acc[1][0] = __builtin_amdgcn_mfma_f32_32x32x16_bf16(af[1], b_cur[0], acc[1][0], 0, 0, 0);
            acc[1][1] = __builtin_amdgcn_mfma_f32_32x32x16_bf16(af[1], b_cur[1], acc[1][1], 0, 0, 0);

            b_cur[0] = b_nxt[0];
            b_cur[1] = b_nxt[1];
        }
        __syncthreads();
    }

    // ---- epilogue: sp = sum_ct tanh(acc)*v ; col-reduce; rows = wr*64+rr*32+(g&3)+8*(g>>2)+4*q2
    float vv[2];
#pragma unroll
    for (int ct = 0; ct < 2; ++ct) vv[ct] = v[(c0 + ct) * 32 + l5];

    float sp[2][16];
#pragma unroll
    for (int rr = 0; rr < 2; ++rr)
#pragma unroll
        for (int g = 0; g < 16; ++g)
            sp[rr][g] = tanh_fast(acc[rr][0][g]) * vv[0] + tanh_fast(acc[rr][1][g]) * vv[1];

#pragma unroll
    for (int rr = 0; rr < 2; ++rr)
#pragma unroll
        for (int g = 0; g < 16; ++g) {
            float s = sp[rr][g];
            s += __shfl_xor(s, 1);
            s += __shfl_xor(s, 2);
            s += __shfl_xor(s, 4);
            s += __shfl_xor(s, 8);
            s += __shfl_xor(s, 16);
            sp[rr][g] = s;
        }

    if (l5 == 0) {
#pragma unroll
        for (int rr = 0; rr < 2; ++rr)
#pragma unroll
            for (int g = 0; g < 16; ++g) {
                int row = wr * 64 + rr * 32 + (g & 3) + 8 * (g >> 2) + 4 * q2;
                red[wc][row] = sp[rr][g];
            }
    }
    __syncthreads();
    if (tid < 128) {
        float s = red[0][tid] + red[1][tid] + red[2][tid] + red[3][tid];
        scores_p[ng * M_ + m0 + tid] = s;
    }
}

// ---------------- K1-fallback (R3 path, used only if ws too small for encT) ----------------
__global__ __launch_bounds__(256, 2) void k_scores_fb(const float* __restrict__ enc,
                                                      const float* __restrict__ decp,
                                                      const __bf16* __restrict__ Wt,
                                                      const float* __restrict__ v,
                                                      float* __restrict__ scores_p) {
    __shared__ __bf16 A_lds[2][64 * 32 * 8];
    __shared__ float red[4][64];
    const int tid = threadIdx.x;
    const int w = tid >> 6, lane = tid & 63;
    const int l5 = lane & 31, q2 = lane >> 5;
    const int bx = blockIdx.x;
    const int xs = bx & 7;
    const int q = bx >> 3;
    const int nt = q & 3;
    const int rg = (q >> 2) * 8 + xs;
    const int m0 = rg * 64;
    const int b = m0 >> 11;
    const int cg0 = nt * 8 + w * 2;
    float dp[2], vvv[2];
#pragma unroll
    for (int ct = 0; ct < 2; ++ct) {
        int col = (cg0 + ct) * 32 + l5;
        dp[ct] = decp[b * H_ + col];
        vvv[ct] = v[col];
    }
    f32x16 acc[2][2];
#pragma unroll
    for (int rt = 0; rt < 2; ++rt)
#pragma unroll
        for (int ct = 0; ct < 2; ++ct)
#pragma unroll
            for (int g = 0; g < 16; ++g) acc[rt][ct][g] = dp[ct];
    const int ko_s = tid & 31;
    const int rbase = (tid >> 5) * 8;
    const float* sbase = &enc[(size_t)(m0 + rbase) * H_ + ko_s * 8];
    {
#pragma unroll
        for (int i = 0; i < 8; ++i) {
            const f32x4* s4 = (const f32x4*)(sbase + (size_t)i * H_);
            int row = rbase + i;
            int cell = row * 32 + ((ko_s & 24) | ((ko_s ^ row) & 7));
            *(bf16x8*)&A_lds[0][cell * 8] = cvt2(s4[0], s4[1]);
        }
    }
    __syncthreads();
    bf16x8 b_cur[2];
#pragma unroll
    for (int ct = 0; ct < 2; ++ct)
        b_cur[ct] = *(const bf16x8*)&Wt[(((size_t)0 * 32 + cg0 + ct) * 64 + lane) * 8];
#pragma unroll 1
    for (int kc = 0; kc < 4; ++kc) {
        const __bf16* buf = A_lds[kc & 1];
#pragma unroll
        for (int sl = 0; sl < 16; ++sl) {
            const int s = kc * 16 + sl;
            int sn = (s + 1) & 63;
            bf16x8 b_nxt[2];
#pragma unroll
            for (int ct = 0; ct < 2; ++ct)
                b_nxt[ct] = *(const bf16x8*)&Wt[(((size_t)sn * 32 + cg0 + ct) * 64 + lane) * 8];
            bf16x8 af[2];
#pragma unroll
            for (int rt = 0; rt < 2; ++rt) {
                int row = rt * 32 + l5;
                int ko = sl * 2 + q2;
                int cell = row * 32 + ((ko & 24) | ((ko ^ row) & 7));
                af[rt] = *(const bf16x8*)&buf[cell * 8];
            }
            acc[0][0] = __builtin_amdgcn_mfma_f32_32x32x16_bf16(af[0], b_cur[0], acc[0][0], 0, 0, 0);
            acc[0][1] = __builtin_amdgcn_mfma_f32_32x32x16_bf16(af[0], b_cur[1], acc[0][1], 0, 0, 0);
            acc[1][0] = __builtin_amdgcn_mfma_f32_32x32x16_bf16(af[1], b_cur[0], acc[1][0], 0, 0, 0);
            acc[1][1] = __builtin_amdgcn_mfma_f32_32x32x16_bf16(af[1], b_cur[1], acc[1][1], 0, 0, 0);
            b_cur[0] = b_nxt[0];
            b_cur[1] = b_nxt[1];
        }
        if (kc < 3) {
            __bf16* dst = A_lds[(kc + 1) & 1];
            const float* sp0 = sbase + (size_t)(kc + 1) * 256;
#pragma unroll
            for (int i = 0; i < 8; ++i) {
                const f32x4* s4 = (const f32x4*)(sp0 + (size_t)i * H_);
                int row = rbase + i;
                int cell = row * 32 + ((ko_s & 24) | ((ko_s ^ row) & 7));
                *(bf16x8*)&dst[cell * 8] = cvt2(s4[0], s4[1]);
            }
        }
        __syncthreads();
    }
    float sp[2][16];
#pragma unroll
    for (int rt = 0; rt < 2; ++rt)
#pragma unroll
        for (int g = 0; g < 16; ++g)
            sp[rt][g] = tanh_fast(acc[rt][0][g]) * vvv[0] + tanh_fast(acc[rt][1][g]) * vvv[1];
#pragma unroll
    for (int rt = 0; rt < 2; ++rt)
#pragma unroll
        for (int g = 0; g < 16; ++g) {
            float s = sp[rt][g];
            s += __shfl_xor(s, 1);
            s += __shfl_xor(s, 2);
            s += __shfl_xor(s, 4);
            s += __shfl_xor(s, 8);
            s += __shfl_xor(s, 16);
            sp[rt][g] = s;
        }
    if (l5 == 0) {
#pragma unroll
        for (int rt = 0; rt < 2; ++rt)
#pragma unroll
            for (int g = 0; g < 16; ++g) {
                int row = rt * 32 + (g & 3) + 8 * (g >> 2) + 4 * q2;
                red[w][row] = sp[rt][g];
            }
    }
    __syncthreads();
    if (tid < 64) {
        float s = red[0][tid] + red[1][tid] + red[2][tid] + red[3][tid];
        scores_p[nt * M_ + m0 + tid] = s;
    }
}

// ---------------- K2: sum partials + masked softmax ----------------
__global__ __launch_bounds__(256) void k_softmax(const float* __restrict__ scores_p,
                                                 const int* __restrict__ mask,
                                                 float* __restrict__ attn) {
    int b = blockIdx.x;
    int tid = threadIdx.x;
    int w = tid >> 6, lane = tid & 63;
    __shared__ float sm[2][4];
    float val[8];
    float mx = -3e38f;
#pragma unroll
    for (int ii = 0; ii < 8; ++ii) {
        int idx = b * T_ + tid + ii * 256;
        float s = scores_p[idx] + scores_p[M_ + idx] + scores_p[2 * M_ + idx] + scores_p[3 * M_ + idx];
        s = (mask[idx] == 0) ? -1e9f : s;
        val[ii] = s;
        mx = fmaxf(mx, s);
    }
#pragma unroll
    for (int m = 1; m <= 32; m <<= 1) mx = fmaxf(mx, __shfl_xor(mx, m));
    if (lane == 0) sm[0][w] = mx;
    __syncthreads();
    mx = fmaxf(fmaxf(sm[0][0], sm[0][1]), fmaxf(sm[0][2], sm[0][3]));
    float lsum = 0.f;
#pragma unroll
    for (int ii = 0; ii < 8; ++ii) {
        val[ii] = __expf(val[ii] - mx);
        lsum += val[ii];
    }
#pragma unroll
    for (int m = 1; m <= 32; m <<= 1) lsum += __shfl_xor(lsum, m);
    if (lane == 0) sm[1][w] = lsum;
    __syncthreads();
    float inv = 1.0f / (sm[1][0] + sm[1][1] + sm[1][2] + sm[1][3]);
#pragma unroll
    for (int ii = 0; ii < 8; ++ii)
        attn[b * T_ + tid + ii * 256] = val[ii] * inv;
}

// ---------------- K3: context[b,h] = sum_t attn[b,t]*enc[b,t,h] (fp32, no atomics) ----------
__global__ __launch_bounds__(512) void k_context(const float* __restrict__ enc,
                                                 const float* __restrict__ attn,
                                                 float* __restrict__ ctx) {
    __shared__ f32x4 cred[8][32];
    int bx = blockIdx.x;
    int b = bx >> 3, hc = bx & 7;
    int tid = threadIdx.x;
    int wv = tid >> 6, lane = tid & 63;
    int l5 = lane & 31, tq2 = lane >> 5;
    int h = hc * 128 + l5 * 4;
    const float* ap = &attn[b * T_ + wv * 256 + tq2];
    const float* ep = &enc[((size_t)b * T_ + wv * 256 + tq2) * H_ + h];
    f32x4 acc = {0.f, 0.f, 0.f, 0.f};
#pragma unroll 8
    for (int i = 0; i < 128; ++i) {
        float a = ap[2 * i];
        f32x4 e = *(const f32x4*)(ep + (size_t)2 * i * H_);
        acc += a * e;
    }
#pragma unroll
    for (int c = 0; c < 4; ++c) acc[c] += __shfl_xor(acc[c], 32);
    if (tq2 == 0) cred[wv][l5] = acc;
    __syncthreads();
    if (tid < 32) {
        f32x4 r = cred[0][tid];
#pragma unroll
        for (int j = 1; j < 8; ++j) r += cred[j][tid];
        *(f32x4*)&ctx[b * H_ + hc * 128 + tid * 4] = r;
    }
}

extern "C" void kernel_launch(void* const* d_in, const int* in_sizes, int n_in,
                              void* d_out, int out_size, void* d_ws, size_t ws_size,
                              hipStream_t stream) {
    (void)in_sizes; (void)n_in; (void)out_size;
    const float* dec  = (const float*)d_in[0];
    const float* enc  = (const float*)d_in[1];
    const int*   mask = (const int*)d_in[2];
    const float* We   = (const float*)d_in[3];
    const float* Wd   = (const float*)d_in[4];
    const float* v    = (const float*)d_in[5];

    float* out = (float*)d_out;                 // [0,32768) context ; [32768,98304) attn
    char* ws = (char*)d_ws;
    float*  decp     = (float*)ws;                          // 128 KB
    float*  scores_p = (float*)(ws + 131072);               // 1 MB (4 partials)
    __bf16* Wt       = (__bf16*)(ws + 131072 + 1048576);    // 2 MB
    __bf16* encT     = (__bf16*)(ws + 3276800);             // 128 MB fragment-major enc

    const size_t NEED = 3276800ull + (size_t)M_ * H_ * 2ull;

    k_prep<<<1024, 256, 0, stream>>>(We, Wt, dec, Wd, decp);
    if (ws_size >= NEED) {
        k_conv  <<<512, 256, 0, stream>>>(enc, encT);
        k_scores<<<2048, 512, 0, stream>>>(encT, decp, Wt, v, scores_p);
    } else {
        k_scores_fb<<<4096, 256, 0, stream>>>(enc, decp, Wt, v, scores_p);
    }
    k_softmax<<<32, 256, 0, stream>>>(scores_p, mask, out + B_ * H_);
    k_context<<<256, 512, 0, stream>>>(enc, out + B_ * H_, out);
}